// Round 2
// 30725.381 us; speedup vs baseline: 1.4024x; 1.4024x over previous
//
#include <hip/hip_runtime.h>
#include <cstdint>
#include <cmath>

// RSSMCore: T=64 sequential steps. Per step:
//   x   = elu(gather(W_in rows for z one-hots + action) + b_in)        [256,1000]
//   gi  = x@W_ih + b_ih   [256,6144];  gh = h@W_hh + b_hh [256,6144]
//   h   = GRU gates (r,z,n) from gi,gh,h                               [256,2048]
//   q1  = elu([h|feat_t]@Wq1 + bq1)    [256,1000];  post = q1@Wq2+bq2  [256,1024] -> out[1,t]
//   p1  = elu(h@Wp1 + bp1)             [256,1000];  prior= p1@Wp2+bp2  [256,1024] -> out[0,t]
//   sample: idx[b,c] = argmax_k(post[b,c,k] + gumbel(threefry bits)), feeds next x
//
// GEMM math: every f32 product taken exactly in f64, accumulated in f64 with
// k strictly ascending (bit-matches the previously-passing scalar kernel).
// The f64 work runs on v_mfma_f64_16x16x4_f64 — but since the fragment layout
// on gfx950 proved different from my CDNA2/3 assumption (round-1 fail), each
// block now SELF-CALIBRATES: 3 probe MFMAs on small integers derive the
// per-lane D row/col map and the A/B lane maps, then VERIFY the full
// A*B->D contract exactly. On any mismatch the block falls back to a scalar
// f64-fma path with identical numerics. Guaranteed-correct either way.

#define GRU_H 2048
#define NB    256      // batch
#define TT    64       // time steps
#define MLP_N 1000
#define ZF    1024
#define FDIM_ 1024
#define G3    6144     // 3*GRU_H

typedef __attribute__((ext_vector_type(4))) double f64x4;

// ---------------- threefry2x32 (JAX-compatible, 20 rounds) ----------------
__host__ __device__ inline uint32_t rotl32(uint32_t v, int r) {
  return (v << r) | (v >> (32 - r));
}

__host__ __device__ inline void threefry2x32(uint32_t k0, uint32_t k1,
                                             uint32_t x0, uint32_t x1,
                                             uint32_t& o0, uint32_t& o1) {
  const uint32_t ks0 = k0, ks1 = k1, ks2 = k0 ^ k1 ^ 0x1BD11BDAu;
  x0 += ks0; x1 += ks1;
#define TFR(r) { x0 += x1; x1 = rotl32(x1, r); x1 ^= x0; }
  TFR(13) TFR(15) TFR(26) TFR(6)   x0 += ks1; x1 += ks2 + 1u;
  TFR(17) TFR(29) TFR(16) TFR(24)  x0 += ks2; x1 += ks0 + 2u;
  TFR(13) TFR(15) TFR(26) TFR(6)   x0 += ks0; x1 += ks1 + 3u;
  TFR(17) TFR(29) TFR(16) TFR(24)  x0 += ks1; x1 += ks2 + 4u;
  TFR(13) TFR(15) TFR(26) TFR(6)   x0 += ks2; x1 += ks0 + 5u;
#undef TFR
  o0 = x0; o1 = x1;
}

// uniform bits -> f32 gumbel, matching jax: u = (bits>>9|0x3f800000 as float)-1 (+tiny clamp)
// then -log(-log(u)) with both logs computed in f64 and rounded to f32.
__device__ inline float gumbel32(uint32_t bits) {
  float f = __uint_as_float((bits >> 9) | 0x3F800000u) - 1.0f;
  float u = f + 1.17549435e-38f;           // == tiny when f==0, else f (exact f32 add)
  float l1 = (float)log((double)u);        // log(u) < 0
  float l2 = (float)log(-(double)l1);
  return -l2;
}

// ---------------- x kernel: gather-sum of W_in rows + elu ----------------
__global__ __launch_bounds__(256) void x_kernel(
    const float* __restrict__ W_in, const float* __restrict__ b_in,
    const int* __restrict__ actions, const int* __restrict__ idxb,
    float* __restrict__ x, int t) {
  __shared__ int rows[33];
  const int b = blockIdx.x;
  if (threadIdx.x < 32 && t != 0)
    rows[threadIdx.x] = threadIdx.x * 32 + idxb[b * 32 + threadIdx.x];
  if (threadIdx.x == 32)
    rows[32] = ZF + ((t == 0) ? 0 : actions[(size_t)(t - 1) * NB + b]);
  __syncthreads();
  for (int j = threadIdx.x; j < MLP_N; j += 256) {
    double s = (double)b_in[j] + (double)W_in[(size_t)rows[32] * MLP_N + j];
    if (t != 0) {
#pragma unroll
      for (int c = 0; c < 32; ++c)
        s += (double)W_in[(size_t)rows[c] * MLP_N + j];
    }
    s = (s > 0.0) ? s : expm1(s);
    x[(size_t)b * MLP_N + j] = (float)s;
  }
}

// ---------------- GRU gate kernel ----------------
__global__ __launch_bounds__(256) void gru_gate(
    const float* __restrict__ gi, const float* __restrict__ gh,
    float* __restrict__ h) {
  const int i = blockIdx.x * 256 + threadIdx.x;      // < NB*GRU_H
  const int b = i >> 11, d = i & (GRU_H - 1);
  const size_t gb = (size_t)b * G3;
  const double ir = gi[gb + d], iz = gi[gb + GRU_H + d], inn = gi[gb + 2 * GRU_H + d];
  const double hr = gh[gb + d], hz = gh[gb + GRU_H + d], hn = gh[gb + 2 * GRU_H + d];
  const double r = 1.0 / (1.0 + exp(-(ir + hr)));
  const double z = 1.0 / (1.0 + exp(-(iz + hz)));
  const double n = tanh(inn + r * hn);
  const double hp = (double)h[i];
  h[i] = (float)((1.0 - z) * n + z * hp);
}

// ---------------- sampling kernel ----------------
__global__ __launch_bounds__(256) void sample_kernel(
    const float* __restrict__ post, int* __restrict__ idxb,
    uint32_t fk0, uint32_t fk1) {
  const int u = blockIdx.x * 256 + threadIdx.x;      // 0..8191
  const int b = u >> 5, c = u & 31;                  // b in [0,256)
  const float* p = post + (size_t)b * ZF + c * 32;
  float bv = 0.f; int bi = 0;
  for (int k = 0; k < 32; ++k) {
    const uint32_t j = (uint32_t)(b * ZF + c * 32 + k);
    uint32_t o0, o1;
    threefry2x32(fk0, fk1, 0u, j, o0, o1);
    const float v = p[k] + gumbel32(o0 ^ o1);
    if (k == 0) { bv = v; }
    else if (v > bv) { bv = v; bi = k; }   // strict > keeps FIRST max
  }
  idxb[b * 32 + c] = bi;
}

// ---------------- self-calibrating MFMA-f64 GEMM ------------------------
// C = A@B + bias (optional elu). A is [256 x K] row-major, optionally concat
// of A0 (k<K0) and A1. B is [K x N] row-major. blockIdx.z picks P0/P1.
struct GemmP {
  const float* A0; const float* A1;
  int K0, K, lda0, lda1;
  const float* B; int N;
  const float* bias;
  float* out; int ldo;
  int epi;   // 0 = none, 1 = elu
};

// Block = 256 threads = 4 waves arranged WM x WN. Wave tile (16*TM16)x(16*TN16).
template<int WM, int WN, int TM16, int TN16>
__global__ __launch_bounds__(256) void gemm_mfma(GemmP P0, GemmP P1) {
  static_assert(WM * WN == 4, "4 waves per block");
  constexpr int BM = 16 * TM16 * WM;
  constexpr int BN = 16 * TN16 * WN;
  constexpr int BK = 64;
  constexpr int BK4 = BK / 4;
  constexpr int BN4 = BN / 4;

  const GemmP p = (blockIdx.z == 0) ? P0 : P1;
  __shared__ float As[BM][BK + 4];
  __shared__ float Bs[BK][BN + 4];
  __shared__ int s_ok;
  const int tid = threadIdx.x;
  const int wave = tid >> 6;
  const int lane = tid & 63;
  const int lr = lane & 15;
  const int lg = lane >> 4;
  const int wm = wave / WN;
  const int wn = wave % WN;
  const int m0 = blockIdx.y * BM;
  const int n0 = blockIdx.x * BN;
  const int mw = wm * (16 * TM16);
  const int nw = wn * (16 * TN16);

  // ---- layout probe: derive per-lane maps from 3 integer MFMAs ----
  // M1: A=lane, B=1 -> D[i][*] = rowsum(i): 4i+96 (A 16-grouped: lane=i+16k)
  //                                     or 16i+6 (A 4-grouped:  lane=4i+k)
  // M2: A=1, B=lane -> colsum(j), same encodings for the B map.
  // M3: A=lane, B=lane -> exact integer cross-check of the full contract.
  const f64x4 z4 = {0.0, 0.0, 0.0, 0.0};
  f64x4 r1 = __builtin_amdgcn_mfma_f64_16x16x4f64((double)lane, 1.0, z4, 0, 0, 0);
  f64x4 r2 = __builtin_amdgcn_mfma_f64_16x16x4f64(1.0, (double)lane, z4, 0, 0, 0);
  f64x4 r3 = __builtin_amdgcn_mfma_f64_16x16x4f64((double)lane, (double)lane, z4, 0, 0, 0);
  int ok = 1, candA = 0, candB = 0;
  int ROW[4], COL[4];
#pragma unroll
  for (int m = 0; m < 4; ++m) {
    const int v = (int)r1[m];
    if ((double)v != r1[m]) ok = 0;
    if (v >= 96 && v <= 156 && (v & 3) == 0) {
      ROW[m] = (v - 96) >> 2; if (candA == 2) ok = 0; candA = 1;
    } else if (v >= 6 && v <= 246 && (v & 15) == 6) {
      ROW[m] = (v - 6) >> 4;  if (candA == 1) ok = 0; candA = 2;
    } else { ROW[m] = 0; ok = 0; }
    const int w = (int)r2[m];
    if ((double)w != r2[m]) ok = 0;
    if (w >= 96 && w <= 156 && (w & 3) == 0) {
      COL[m] = (w - 96) >> 2; if (candB == 2) ok = 0; candB = 1;
    } else if (w >= 6 && w <= 246 && (w & 15) == 6) {
      COL[m] = (w - 6) >> 4;  if (candB == 1) ok = 0; candB = 2;
    } else { COL[m] = 0; ok = 0; }
  }
  if (ok) {
#pragma unroll
    for (int m = 0; m < 4; ++m) {
      double e = 0.0;
#pragma unroll
      for (int k = 0; k < 4; ++k) {
        const double va = (candA == 1) ? (double)(ROW[m] + 16 * k)
                                       : (double)(4 * ROW[m] + k);
        const double vb = (candB == 1) ? (double)(COL[m] + 16 * k)
                                       : (double)(4 * COL[m] + k);
        e += va * vb;
      }
      if (r3[m] != e) ok = 0;
    }
  }
  if (tid == 0) s_ok = 1;
  __syncthreads();
  if (!ok) s_ok = 0;
  __syncthreads();
  const bool bok = (s_ok != 0);
  if (!bok) {     // fixed map for the scalar fallback
#pragma unroll
    for (int m = 0; m < 4; ++m) { ROW[m] = 4 * lg + m; COL[m] = lr; }
  }
  // fragment-read lane maps (per decoded candidate)
  const int rowA = (candA == 2) ? (lane >> 2) : lr;
  const int kA   = (candA == 2) ? (lane & 3)  : lg;
  const int colB = (candB == 2) ? (lane >> 2) : lr;
  const int kB   = (candB == 2) ? (lane & 3)  : lg;

  f64x4 acc[TM16][TN16];
#pragma unroll
  for (int i = 0; i < TM16; ++i)
#pragma unroll
    for (int j = 0; j < TN16; ++j) acc[i][j] = z4;

  const int ktiles = (p.K + BK - 1) / BK;
  for (int kt = 0; kt < ktiles; ++kt) {
    const int k0 = kt * BK;
    // ---- load A tile (BM x BK), float4 along K, coalesced ----
    for (int q = tid; q < BM * BK4; q += 256) {
      const int row = q / BK4;
      const int kq  = (q % BK4) << 2;
      const int gk  = k0 + kq;
      const float* src; int col;
      if (gk < p.K0) { src = p.A0 + (size_t)(m0 + row) * p.lda0; col = gk; }
      else           { src = p.A1 + (size_t)(m0 + row) * p.lda1; col = gk - p.K0; }
      float4 v;
      if (gk + 3 < p.K) v = *(const float4*)(src + col);
      else {
        float tmp[4];
#pragma unroll
        for (int e = 0; e < 4; ++e) tmp[e] = (gk + e < p.K) ? src[col + e] : 0.f;
        v = make_float4(tmp[0], tmp[1], tmp[2], tmp[3]);
      }
      *(float4*)&As[row][kq] = v;
    }
    // ---- load B tile (BK x BN) ----
    for (int q = tid; q < BK * BN4; q += 256) {
      const int kr = q / BN4;
      const int nq = (q % BN4) << 2;
      const int gk = k0 + kr, gn = n0 + nq;
      float4 v = make_float4(0.f, 0.f, 0.f, 0.f);
      if (gk < p.K) {
        const float* src = p.B + (size_t)gk * p.N;
        if (gn + 3 < p.N) v = *(const float4*)(src + gn);
        else {
          float tmp[4];
#pragma unroll
          for (int e = 0; e < 4; ++e) tmp[e] = (gn + e < p.N) ? src[gn + e] : 0.f;
          v = make_float4(tmp[0], tmp[1], tmp[2], tmp[3]);
        }
      }
      *(float4*)&Bs[kr][nq] = v;
    }
    __syncthreads();
    if (bok) {
      // ---- MFMA path: k strictly ascending, 4 per instruction ----
#pragma unroll
      for (int ks = 0; ks < BK4; ++ks) {
        double a[TM16], b[TN16];
#pragma unroll
        for (int i = 0; i < TM16; ++i) a[i] = (double)As[mw + i * 16 + rowA][ks * 4 + kA];
#pragma unroll
        for (int j = 0; j < TN16; ++j) b[j] = (double)Bs[ks * 4 + kB][nw + j * 16 + colB];
#pragma unroll
        for (int i = 0; i < TM16; ++i)
#pragma unroll
          for (int j = 0; j < TN16; ++j)
            acc[i][j] = __builtin_amdgcn_mfma_f64_16x16x4f64(a[i], b[j], acc[i][j], 0, 0, 0);
      }
    } else {
      // ---- scalar fallback: identical fma sequence to the passing kernel ----
#pragma unroll 4
      for (int kk = 0; kk < BK; ++kk) {
#pragma unroll
        for (int i = 0; i < TM16; ++i)
#pragma unroll
          for (int j = 0; j < TN16; ++j)
#pragma unroll
            for (int m = 0; m < 4; ++m)
              acc[i][j][m] = fma((double)As[mw + i * 16 + ROW[m]][kk],
                                 (double)Bs[kk][nw + j * 16 + COL[m]],
                                 acc[i][j][m]);
      }
    }
    __syncthreads();
  }
  // ---- epilogue (shared by both paths, uses derived/fixed maps) ----
#pragma unroll
  for (int i = 0; i < TM16; ++i)
#pragma unroll
    for (int j = 0; j < TN16; ++j)
#pragma unroll
      for (int m = 0; m < 4; ++m) {
        const int row = m0 + mw + i * 16 + ROW[m];
        const int col = n0 + nw + j * 16 + COL[m];
        if (col < p.N) {
          double v = acc[i][j][m] + (double)p.bias[col];
          if (p.epi) v = (v > 0.0) ? v : expm1(v);
          p.out[(size_t)row * p.ldo + col] = (float)v;
        }
      }
}

// ---------------- host ----------------
extern "C" void kernel_launch(void* const* d_in, const int* in_sizes, int n_in,
                              void* d_out, int out_size, void* d_ws, size_t ws_size,
                              hipStream_t stream) {
  const float* features = (const float*)d_in[0];
  const int*   actions  = (const int*)  d_in[1];
  const float* W_in = (const float*)d_in[2];
  const float* b_in = (const float*)d_in[3];
  const float* W_ih = (const float*)d_in[4];
  const float* W_hh = (const float*)d_in[5];
  const float* b_ih = (const float*)d_in[6];
  const float* b_hh = (const float*)d_in[7];
  const float* Wp1  = (const float*)d_in[8];
  const float* bp1  = (const float*)d_in[9];
  const float* Wp2  = (const float*)d_in[10];
  const float* bp2  = (const float*)d_in[11];
  const float* Wq1  = (const float*)d_in[12];
  const float* bq1  = (const float*)d_in[13];
  const float* Wq2  = (const float*)d_in[14];
  const float* bq2  = (const float*)d_in[15];
  float* out = (float*)d_out;

  // workspace layout (bytes): ~17.9 MB total
  char* ws = (char*)d_ws;
  float* h   = (float*)(ws + 0);                 // 256*2048*4 = 2 MB
  float* x   = (float*)(ws + (2u << 20));        // 256*1000*4
  float* gi  = (float*)(ws + (3u << 20));        // 256*6144*4 = 6 MB
  float* gh  = (float*)(ws + (9u << 20));
  float* q1b = (float*)(ws + (15u << 20));       // 256*1000*4
  float* p1b = (float*)(ws + (16u << 20));
  int*   idxb = (int*)  (ws + (17u << 20));      // 256*32*4

  hipMemsetAsync(h, 0, (size_t)NB * GRU_H * sizeof(float), stream);

  for (int t = 0; t < TT; ++t) {
    // 1) x_t from previous sample (z one-hots) + previous action
    x_kernel<<<dim3(NB), 256, 0, stream>>>(W_in, b_in, actions, idxb, x, t);

    // 2) gi = x@W_ih + b_ih ; gh = h@W_hh + b_hh   (dual via blockIdx.z)
    //    64x64 block, 4 waves 2x2, wave 32x32 (4 mfma accs). 768 blocks = 3/CU.
    GemmP pgi { x, x, MLP_N, MLP_N, MLP_N, MLP_N, W_ih, G3, b_ih, gi, G3, 0 };
    GemmP pgh { h, h, GRU_H, GRU_H, GRU_H, GRU_H, W_hh, G3, b_hh, gh, G3, 0 };
    gemm_mfma<2, 2, 2, 2><<<dim3(G3 / 64, NB / 64, 2), 256, 0, stream>>>(pgi, pgh);

    // 3) GRU gates -> h (in place)
    gru_gate<<<dim3(NB * GRU_H / 256), 256, 0, stream>>>(gi, gh, h);

    // 4) q1 = elu([h|feat_t]@Wq1+bq1) ; p1 = elu(h@Wp1+bp1)
    const float* feat_t = features + (size_t)t * NB * FDIM_;
    GemmP pq1 { h, feat_t, GRU_H, GRU_H + FDIM_, GRU_H, FDIM_, Wq1, MLP_N, bq1, q1b, MLP_N, 1 };
    GemmP pp1 { h, h,      GRU_H, GRU_H,         GRU_H, GRU_H, Wp1, MLP_N, bp1, p1b, MLP_N, 1 };
    gemm_mfma<2, 2, 1, 1><<<dim3((MLP_N + 31) / 32, NB / 32, 2), 256, 0, stream>>>(pq1, pp1);

    // 5) post = q1@Wq2+bq2 -> out[1,t] ; prior = p1@Wp2+bp2 -> out[0,t]
    float* postout  = out + (size_t)(TT + t) * NB * ZF;
    float* priorout = out + (size_t)t * NB * ZF;
    GemmP pq2 { q1b, q1b, MLP_N, MLP_N, MLP_N, MLP_N, Wq2, ZF, bq2, postout,  ZF, 0 };
    GemmP pp2 { p1b, p1b, MLP_N, MLP_N, MLP_N, MLP_N, Wp2, ZF, bp2, priorout, ZF, 0 };
    gemm_mfma<2, 2, 1, 1><<<dim3(ZF / 32, NB / 32, 2), 256, 0, stream>>>(pq2, pp2);

    // 6) categorical sample with fold_in(key(42), t)
    uint32_t fk0, fk1;
    threefry2x32(0u, 42u, 0u, (uint32_t)t, fk0, fk1);   // fold_in: enc((0,42),(0,t))
    sample_kernel<<<dim3(32), 256, 0, stream>>>(postout, idxb, fk0, fk1);
  }
}